// Round 6
// baseline (2325.303 us; speedup 1.0000x reference)
//
#include <hip/hip_runtime.h>

// Encoder: point MLP (4->64->128->256->256) via split-bf16 MFMA + segment-mean
// pool + fp32 latent MLP.
// Round 6: PTS 64 -> 32 (LDS 25.6 KB -> 6 blocks/CU, 24 waves/CU) to attack
// the latency-bound regime (both pipes <21% busy at 12 waves/CU).
// Math identical to rounds 4/5 (passed, absmax 0):
// - Weights pre-split hi/lo bf16 (2 MFMAs per product), fragment-major.
// - A and B fragments use the SAME (lane,e)->k map, so k-order cancels.
// - C/D layout: col=lane&15, row=(lane>>4)*4+reg (HW-verified m89).

#define NB    4096
#define NTOT  1048576
#define PTS   32
#define ATILES (PTS / 16)         // 2
#define OUT_HALF (NB * 256)       // 1048576 floats
#define WSPLIT_ELEMS 106496       // 8192 + 32768 + 65536 frag-elems per array

typedef __attribute__((ext_vector_type(8))) short short8;
typedef __attribute__((ext_vector_type(4))) float f32x4;
typedef unsigned short u16;
typedef unsigned int   u32;

__device__ __forceinline__ float lrelu(float x){ return x > 0.0f ? x : 0.01f * x; }

__device__ __forceinline__ u16 f2bf(float x){            // round-to-nearest-even
  union{float f; u32 u;} v; v.f = x;
  u32 r = v.u + 0x7fffu + ((v.u >> 16) & 1u);
  return (u16)(r >> 16);
}
__device__ __forceinline__ float bf2f(u16 h){
  union{u32 u; float f;} v; v.u = ((u32)h) << 16; return v.f;
}

__device__ __forceinline__ int find_cloud(const int* __restrict__ idx, int j){
  int lo = 0, hi = NB;
  while (lo < hi){
    int mid = (lo + hi) >> 1;
    if (idx[mid] <= j) lo = mid + 1; else hi = mid;
  }
  return lo;
}

// ---- prologue: split W into hi/lo bf16, fragment-major ---------------------
// frag = 512 elems: [lane 0..63][e 0..7]; elem (lane,e) = W[mtg*16+(lane&15)]
// [ks*32+(lane>>4)*8+e]. Layer offsets (u16 elems): L1=0, L2=8192, L3=40960.
__global__ void wsplit_kernel(const float* __restrict__ w1,
                              const float* __restrict__ w2,
                              const float* __restrict__ w3,
                              u16* __restrict__ Whi, u16* __restrict__ Wlo){
  const int tid = blockIdx.x * 256 + threadIdx.x;   // 0..106495
  const float* W; int K, off;
  if (tid < 8192)       { W = w1; K = 64;  off = 0; }
  else if (tid < 40960) { W = w2; K = 128; off = 8192; }
  else                  { W = w3; K = 256; off = 40960; }
  const int t      = tid - off;
  const int fragId = t >> 9;
  const int r      = t & 511;
  const int lane   = r >> 3, e = r & 7;
  const int KS     = K / 32;
  const int ks     = fragId % KS, mtg = fragId / KS;
  const int m      = mtg * 16 + (lane & 15);
  const int k      = ks * 32 + (lane >> 4) * 8 + e;
  const float v = W[(size_t)m * K + k];
  const u16 hi = f2bf(v);
  const u16 lo = f2bf(v - bf2f(hi));
  Whi[tid] = hi; Wlo[tid] = lo;
}

// ---- one MFMA layer: K -> M over 32 points; wave w owns m-quarter ----------
// MTW = M/64 m-tiles per wave; ATILES A-tiles (16 pts each). Bias baked in.
template<int K, int M, int LDSKI, int LDSKO, bool WRITE>
__device__ __forceinline__ void mfma_layer(
    const u16* __restrict__ hin, u16* __restrict__ hout,
    const u16* __restrict__ Whi, const u16* __restrict__ Wlo,
    const float* __restrict__ bias, int w, int lane, f32x4 (*__restrict__ accRet)[4])
{
  constexpr int KS  = K / 32;
  constexpr int MTW = M / 64;
  const int lrow = lane & 15;   // A-row (pt in tile) == B/D col (m in tile)
  const int g    = lane >> 4;   // k-slice group / D row group

  f32x4 acc[ATILES][MTW];
  #pragma unroll
  for (int mt = 0; mt < MTW; ++mt){
    const float bv = bias[(w * MTW + mt) * 16 + lrow];
    #pragma unroll
    for (int a = 0; a < ATILES; ++a){
      acc[a][mt][0] = bv; acc[a][mt][1] = bv; acc[a][mt][2] = bv; acc[a][mt][3] = bv;
    }
  }

  // fragment (mt, ks) lives at (mt*KS + ks)*512 + lane*8 past these bases
  const u16* __restrict__ bptr = Whi + (size_t)(w * MTW) * KS * 512 + lane * 8;
  const u16* __restrict__ lptr = Wlo + (size_t)(w * MTW) * KS * 512 + lane * 8;

  short8 af[ATILES], bh[MTW], bl[MTW];
  #pragma unroll
  for (int a = 0; a < ATILES; ++a)
    af[a] = *reinterpret_cast<const short8*>(hin + (a * 16 + lrow) * LDSKI + g * 8);
  #pragma unroll
  for (int mt = 0; mt < MTW; ++mt){
    bh[mt] = *reinterpret_cast<const short8*>(bptr + (size_t)mt * KS * 512);
    bl[mt] = *reinterpret_cast<const short8*>(lptr + (size_t)mt * KS * 512);
  }

  #pragma unroll
  for (int ks = 0; ks < KS; ++ks){
    short8 af2[ATILES], bh2[MTW], bl2[MTW];
    if (ks + 1 < KS){                                  // compile-time folded
      const int eoff2 = (ks + 1) * 32 + g * 8;
      #pragma unroll
      for (int a = 0; a < ATILES; ++a)
        af2[a] = *reinterpret_cast<const short8*>(hin + (a * 16 + lrow) * LDSKI + eoff2);
      #pragma unroll
      for (int mt = 0; mt < MTW; ++mt){
        bh2[mt] = *reinterpret_cast<const short8*>(bptr + (size_t)(mt * KS + ks + 1) * 512);
        bl2[mt] = *reinterpret_cast<const short8*>(lptr + (size_t)(mt * KS + ks + 1) * 512);
      }
    }
    #pragma unroll
    for (int mt = 0; mt < MTW; ++mt){
      #pragma unroll
      for (int a = 0; a < ATILES; ++a)
        acc[a][mt] = __builtin_amdgcn_mfma_f32_16x16x32_bf16(af[a], bh[mt], acc[a][mt], 0, 0, 0);
      #pragma unroll
      for (int a = 0; a < ATILES; ++a)
        acc[a][mt] = __builtin_amdgcn_mfma_f32_16x16x32_bf16(af[a], bl[mt], acc[a][mt], 0, 0, 0);
    }
    if (ks + 1 < KS){
      #pragma unroll
      for (int a = 0; a < ATILES; ++a) af[a] = af2[a];
      #pragma unroll
      for (int mt = 0; mt < MTW; ++mt){ bh[mt] = bh2[mt]; bl[mt] = bl2[mt]; }
    }
  }

  if constexpr (WRITE){
    #pragma unroll
    for (int a = 0; a < ATILES; ++a)
      #pragma unroll
      for (int mt = 0; mt < MTW; ++mt){
        const int m = (w * MTW + mt) * 16 + lrow;
        #pragma unroll
        for (int r = 0; r < 4; ++r){
          const int pt = a * 16 + g * 4 + r;      // D row = point
          hout[pt * LDSKO + m] = f2bf(lrelu(acc[a][mt][r]));
        }
      }
  } else {
    #pragma unroll
    for (int a = 0; a < ATILES; ++a)
      #pragma unroll
      for (int mt = 0; mt < MTW; ++mt)
        accRet[a][mt] = acc[a][mt];
  }
}

__global__ __launch_bounds__(256, 6)
void point_mfma_kernel(const float* __restrict__ points, const int* __restrict__ idx,
    const float* __restrict__ w0, const float* __restrict__ b0,
    const float* __restrict__ b1, const float* __restrict__ b2,
    const float* __restrict__ b3,
    const u16* __restrict__ Whi, const u16* __restrict__ Wlo,
    float* __restrict__ sums)
{
  // Overlapped LDS arena (25600 B -> 6 blocks/CU):
  //   h2 @ 0     (8704 B)   live: L1-write .. L2-read
  //   h1 @ 8704  (4608 B)   live: L0-write .. L1-read
  //   h3 @ 8704  (16896 B)  live: L2-write .. L3-read (h1 dead by then)
  __shared__ __align__(16) char smem[25600];
  u16 (*h2)[136] = reinterpret_cast<u16(*)[136]>(smem);
  u16 (*h1)[72]  = reinterpret_cast<u16(*)[72]>(smem + 8704);
  u16 (*h3)[264] = reinterpret_cast<u16(*)[264]>(smem + 8704);

  const int t    = threadIdx.x;
  const int base = blockIdx.x * PTS;
  const int w    = t >> 6;
  const int lane = t & 63;

  // L0: 4 -> 64 fp32 straight from global (scalar-broadcast weights)
  {
    const int pt  = t & 31;
    const int grp = t >> 5;       // 0..7, 8 dims each
    const float4 pv = *reinterpret_cast<const float4*>(points + (size_t)(base + pt) * 4);
    #pragma unroll
    for (int j = 0; j < 8; ++j){
      const int m = grp * 8 + j;
      const float4 wv = *reinterpret_cast<const float4*>(w0 + m * 4);
      const float s = b0[m] + pv.x * wv.x + pv.y * wv.y + pv.z * wv.z + pv.w * wv.w;
      h1[pt][m] = f2bf(lrelu(s));
    }
  }
  __syncthreads();
  mfma_layer< 64, 128,  72, 136, true >(&h1[0][0], &h2[0][0], Whi + 0,     Wlo + 0,     b1, w, lane, nullptr);
  __syncthreads();
  mfma_layer<128, 256, 136, 264, true >(&h2[0][0], &h3[0][0], Whi + 8192,  Wlo + 8192,  b2, w, lane, nullptr);
  __syncthreads();
  f32x4 acc3[ATILES][4];
  mfma_layer<256, 256, 264,   1, false>(&h3[0][0], nullptr,   Whi + 40960, Wlo + 40960, b3, w, lane, acc3);

  // segment reduction (bias already baked per point)
  const int lrow = lane & 15;
  const int cF = find_cloud(idx, base);
  const int cL = find_cloud(idx, base + PTS - 1);
  if (cF == cL){
    #pragma unroll
    for (int mt = 0; mt < 4; ++mt){
      float s = 0.0f;
      #pragma unroll
      for (int a = 0; a < ATILES; ++a){
        const f32x4 v = acc3[a][mt];
        s += v[0] + v[1] + v[2] + v[3];
      }
      s += __shfl_xor(s, 16, 64);
      s += __shfl_xor(s, 32, 64);
      if (lane < 16)
        atomicAdd(sums + (size_t)cF * 256 + (w * 4 + mt) * 16 + lrow, s);
    }
  } else {
    const int g = lane >> 4;
    #pragma unroll
    for (int a = 0; a < ATILES; ++a)
      #pragma unroll
      for (int mt = 0; mt < 4; ++mt)
        #pragma unroll
        for (int r = 0; r < 4; ++r){
          const int pt = base + a * 16 + g * 4 + r;
          const int c  = find_cloud(idx, pt);
          atomicAdd(sums + (size_t)c * 256 + (w * 4 + mt) * 16 + lrow, acc3[a][mt][r]);
        }
  }
}

// ---- latent MLP: 4 clouds per block, 256 threads (thread = output dim) ----
__device__ __forceinline__ void lat_accum(const float (*__restrict__ in)[256],
    const float* __restrict__ W, const float* __restrict__ bias, int t, float acc[4])
{
  const float bv = bias[t];
  #pragma unroll
  for (int cl = 0; cl < 4; ++cl) acc[cl] = bv;
  const float4* __restrict__ wrow = reinterpret_cast<const float4*>(W + (size_t)t * 256);
  #pragma unroll 4
  for (int k4 = 0; k4 < 64; ++k4){
    const float4 w = wrow[k4];
    #pragma unroll
    for (int cl = 0; cl < 4; ++cl){
      const float4 a = *reinterpret_cast<const float4*>(&in[cl][k4 * 4]);
      acc[cl] += a.x * w.x + a.y * w.y + a.z * w.z + a.w * w.w;
    }
  }
}

__global__ __launch_bounds__(256)
void latent_kernel(const float* __restrict__ sums, const int* __restrict__ idx,
    const float* __restrict__ lw0, const float* __restrict__ lb0,
    const float* __restrict__ lw1, const float* __restrict__ lb1,
    const float* __restrict__ mw, const float* __restrict__ mb,
    const float* __restrict__ vw, const float* __restrict__ vb,
    float* __restrict__ out)
{
  __shared__ float s_in[4][256];
  __shared__ float s_a[4][256];
  const int t  = threadIdx.x;
  const int c0 = blockIdx.x * 4;

  #pragma unroll
  for (int cl = 0; cl < 4; ++cl){
    const int c = c0 + cl;
    const int cnt = idx[c] - (c ? idx[c - 1] : 0);
    s_in[cl][t] = sums[(size_t)c * 256 + t] / (float)cnt;
  }
  __syncthreads();

  float acc[4];
  lat_accum(s_in, lw0, lb0, t, acc);
  #pragma unroll
  for (int cl = 0; cl < 4; ++cl) s_a[cl][t] = lrelu(acc[cl]);
  __syncthreads();

  lat_accum(s_a, lw1, lb1, t, acc);
  __syncthreads();
  #pragma unroll
  for (int cl = 0; cl < 4; ++cl) s_in[cl][t] = lrelu(acc[cl]);
  __syncthreads();

  float accm[4], accv[4];
  lat_accum(s_in, mw, mb, t, accm);
  lat_accum(s_in, vw, vb, t, accv);
  #pragma unroll
  for (int cl = 0; cl < 4; ++cl){
    out[(size_t)(c0 + cl) * 256 + t]                    = accm[cl];  // mu
    out[(size_t)OUT_HALF + (size_t)(c0 + cl) * 256 + t] = accv[cl];  // log_var
  }
}

extern "C" void kernel_launch(void* const* d_in, const int* in_sizes, int n_in,
                              void* d_out, int out_size, void* d_ws, size_t ws_size,
                              hipStream_t stream) {
  const float* points = (const float*)d_in[0];
  const int*   idx    = (const int*)  d_in[1];
  const float* pw0 = (const float*)d_in[2],  *pb0 = (const float*)d_in[3];
  const float* pw1 = (const float*)d_in[4],  *pb1 = (const float*)d_in[5];
  const float* pw2 = (const float*)d_in[6],  *pb2 = (const float*)d_in[7];
  const float* pw3 = (const float*)d_in[8],  *pb3 = (const float*)d_in[9];
  const float* lw0 = (const float*)d_in[10], *lb0 = (const float*)d_in[11];
  const float* lw1 = (const float*)d_in[12], *lb1 = (const float*)d_in[13];
  const float* mw  = (const float*)d_in[14], *mb  = (const float*)d_in[15];
  const float* vw  = (const float*)d_in[16], *vb  = (const float*)d_in[17];
  float* out  = (float*)d_out;

  const size_t sums_bytes = (size_t)NB * 256 * sizeof(float);      // 4 MB
  const size_t wsplit_bytes = (size_t)WSPLIT_ELEMS * 2;            // 208 KB each
  float* sums; u16* Whi; u16* Wlo;
  if (ws_size >= sums_bytes + 2 * wsplit_bytes){
    sums = (float*)d_ws;
    Whi  = (u16*)((char*)d_ws + sums_bytes);
    Wlo  = Whi + WSPLIT_ELEMS;
  } else {
    // fallback: mu-half holds Wsplit (dead until latent writes mu at the end),
    // logvar-half holds sums (latent reads them just before writing log_var)
    Whi  = (u16*)d_out;
    Wlo  = Whi + WSPLIT_ELEMS;
    sums = out + OUT_HALF;
  }

  hipMemsetAsync(sums, 0, sums_bytes, stream);
  wsplit_kernel<<<WSPLIT_ELEMS / 256, 256, 0, stream>>>(pw1, pw2, pw3, Whi, Wlo);
  point_mfma_kernel<<<NTOT / PTS, 256, 0, stream>>>(points, idx,
      pw0, pb0, pb1, pb2, pb3, Whi, Wlo, sums);
  latent_kernel<<<NB / 4, 256, 0, stream>>>(sums, idx,
      lw0, lb0, lw1, lb1, mw, mb, vw, vb, out);
}

// Round 7
// 2041.331 us; speedup vs baseline: 1.1391x; 1.1391x over previous
//
#include <hip/hip_runtime.h>

// Encoder: point MLP (4->64->128->256->256) via split-bf16 MFMA + segment-mean
// pool + fp32 latent MLP.
// Round 7: PTS=32 kept (25.6 KB LDS), but launch_bounds(256,4) instead of
// (256,6) — round 6's forced 6-waves/EU cap (=> 40 VGPR) spilled acc/frags
// to scratch (WRITE_SIZE 16->373 MB, 10x regression). Cap 128 VGPR un-spills;
// occupancy lands VGPR-limited at ~4 blocks/CU (16 waves), still > round 5.
// Math identical to rounds 4/5/6 (passed, absmax 0):
// - Weights pre-split hi/lo bf16 (2 MFMAs per product), fragment-major.
// - A and B fragments use the SAME (lane,e)->k map, so k-order cancels.
// - C/D layout: col=lane&15, row=(lane>>4)*4+reg (HW-verified m89).

#define NB    4096
#define NTOT  1048576
#define PTS   32
#define ATILES (PTS / 16)         // 2
#define OUT_HALF (NB * 256)       // 1048576 floats
#define WSPLIT_ELEMS 106496       // 8192 + 32768 + 65536 frag-elems per array

typedef __attribute__((ext_vector_type(8))) short short8;
typedef __attribute__((ext_vector_type(4))) float f32x4;
typedef unsigned short u16;
typedef unsigned int   u32;

__device__ __forceinline__ float lrelu(float x){ return x > 0.0f ? x : 0.01f * x; }

__device__ __forceinline__ u16 f2bf(float x){            // round-to-nearest-even
  union{float f; u32 u;} v; v.f = x;
  u32 r = v.u + 0x7fffu + ((v.u >> 16) & 1u);
  return (u16)(r >> 16);
}
__device__ __forceinline__ float bf2f(u16 h){
  union{u32 u; float f;} v; v.u = ((u32)h) << 16; return v.f;
}

__device__ __forceinline__ int find_cloud(const int* __restrict__ idx, int j){
  int lo = 0, hi = NB;
  while (lo < hi){
    int mid = (lo + hi) >> 1;
    if (idx[mid] <= j) lo = mid + 1; else hi = mid;
  }
  return lo;
}

// ---- prologue: split W into hi/lo bf16, fragment-major ---------------------
// frag = 512 elems: [lane 0..63][e 0..7]; elem (lane,e) = W[mtg*16+(lane&15)]
// [ks*32+(lane>>4)*8+e]. Layer offsets (u16 elems): L1=0, L2=8192, L3=40960.
__global__ void wsplit_kernel(const float* __restrict__ w1,
                              const float* __restrict__ w2,
                              const float* __restrict__ w3,
                              u16* __restrict__ Whi, u16* __restrict__ Wlo){
  const int tid = blockIdx.x * 256 + threadIdx.x;   // 0..106495
  const float* W; int K, off;
  if (tid < 8192)       { W = w1; K = 64;  off = 0; }
  else if (tid < 40960) { W = w2; K = 128; off = 8192; }
  else                  { W = w3; K = 256; off = 40960; }
  const int t      = tid - off;
  const int fragId = t >> 9;
  const int r      = t & 511;
  const int lane   = r >> 3, e = r & 7;
  const int KS     = K / 32;
  const int ks     = fragId % KS, mtg = fragId / KS;
  const int m      = mtg * 16 + (lane & 15);
  const int k      = ks * 32 + (lane >> 4) * 8 + e;
  const float v = W[(size_t)m * K + k];
  const u16 hi = f2bf(v);
  const u16 lo = f2bf(v - bf2f(hi));
  Whi[tid] = hi; Wlo[tid] = lo;
}

// ---- one MFMA layer: K -> M over 32 points; wave w owns m-quarter ----------
// MTW = M/64 m-tiles per wave; ATILES A-tiles (16 pts each). Bias baked in.
template<int K, int M, int LDSKI, int LDSKO, bool WRITE>
__device__ __forceinline__ void mfma_layer(
    const u16* __restrict__ hin, u16* __restrict__ hout,
    const u16* __restrict__ Whi, const u16* __restrict__ Wlo,
    const float* __restrict__ bias, int w, int lane, f32x4 (*__restrict__ accRet)[4])
{
  constexpr int KS  = K / 32;
  constexpr int MTW = M / 64;
  const int lrow = lane & 15;   // A-row (pt in tile) == B/D col (m in tile)
  const int g    = lane >> 4;   // k-slice group / D row group

  f32x4 acc[ATILES][MTW];
  #pragma unroll
  for (int mt = 0; mt < MTW; ++mt){
    const float bv = bias[(w * MTW + mt) * 16 + lrow];
    #pragma unroll
    for (int a = 0; a < ATILES; ++a){
      acc[a][mt][0] = bv; acc[a][mt][1] = bv; acc[a][mt][2] = bv; acc[a][mt][3] = bv;
    }
  }

  // fragment (mt, ks) lives at (mt*KS + ks)*512 + lane*8 past these bases
  const u16* __restrict__ bptr = Whi + (size_t)(w * MTW) * KS * 512 + lane * 8;
  const u16* __restrict__ lptr = Wlo + (size_t)(w * MTW) * KS * 512 + lane * 8;

  short8 af[ATILES], bh[MTW], bl[MTW];
  #pragma unroll
  for (int a = 0; a < ATILES; ++a)
    af[a] = *reinterpret_cast<const short8*>(hin + (a * 16 + lrow) * LDSKI + g * 8);
  #pragma unroll
  for (int mt = 0; mt < MTW; ++mt){
    bh[mt] = *reinterpret_cast<const short8*>(bptr + (size_t)mt * KS * 512);
    bl[mt] = *reinterpret_cast<const short8*>(lptr + (size_t)mt * KS * 512);
  }

  #pragma unroll
  for (int ks = 0; ks < KS; ++ks){
    short8 af2[ATILES], bh2[MTW], bl2[MTW];
    if (ks + 1 < KS){                                  // compile-time folded
      const int eoff2 = (ks + 1) * 32 + g * 8;
      #pragma unroll
      for (int a = 0; a < ATILES; ++a)
        af2[a] = *reinterpret_cast<const short8*>(hin + (a * 16 + lrow) * LDSKI + eoff2);
      #pragma unroll
      for (int mt = 0; mt < MTW; ++mt){
        bh2[mt] = *reinterpret_cast<const short8*>(bptr + (size_t)(mt * KS + ks + 1) * 512);
        bl2[mt] = *reinterpret_cast<const short8*>(lptr + (size_t)(mt * KS + ks + 1) * 512);
      }
    }
    #pragma unroll
    for (int mt = 0; mt < MTW; ++mt){
      #pragma unroll
      for (int a = 0; a < ATILES; ++a)
        acc[a][mt] = __builtin_amdgcn_mfma_f32_16x16x32_bf16(af[a], bh[mt], acc[a][mt], 0, 0, 0);
      #pragma unroll
      for (int a = 0; a < ATILES; ++a)
        acc[a][mt] = __builtin_amdgcn_mfma_f32_16x16x32_bf16(af[a], bl[mt], acc[a][mt], 0, 0, 0);
    }
    if (ks + 1 < KS){
      #pragma unroll
      for (int a = 0; a < ATILES; ++a) af[a] = af2[a];
      #pragma unroll
      for (int mt = 0; mt < MTW; ++mt){ bh[mt] = bh2[mt]; bl[mt] = bl2[mt]; }
    }
  }

  if constexpr (WRITE){
    #pragma unroll
    for (int a = 0; a < ATILES; ++a)
      #pragma unroll
      for (int mt = 0; mt < MTW; ++mt){
        const int m = (w * MTW + mt) * 16 + lrow;
        #pragma unroll
        for (int r = 0; r < 4; ++r){
          const int pt = a * 16 + g * 4 + r;      // D row = point
          hout[pt * LDSKO + m] = f2bf(lrelu(acc[a][mt][r]));
        }
      }
  } else {
    #pragma unroll
    for (int a = 0; a < ATILES; ++a)
      #pragma unroll
      for (int mt = 0; mt < MTW; ++mt)
        accRet[a][mt] = acc[a][mt];
  }
}

__global__ __launch_bounds__(256, 4)
void point_mfma_kernel(const float* __restrict__ points, const int* __restrict__ idx,
    const float* __restrict__ w0, const float* __restrict__ b0,
    const float* __restrict__ b1, const float* __restrict__ b2,
    const float* __restrict__ b3,
    const u16* __restrict__ Whi, const u16* __restrict__ Wlo,
    float* __restrict__ sums)
{
  // Overlapped LDS arena (25600 B):
  //   h2 @ 0     (8704 B)   live: L1-write .. L2-read
  //   h1 @ 8704  (4608 B)   live: L0-write .. L1-read
  //   h3 @ 8704  (16896 B)  live: L2-write .. L3-read (h1 dead by then)
  __shared__ __align__(16) char smem[25600];
  u16 (*h2)[136] = reinterpret_cast<u16(*)[136]>(smem);
  u16 (*h1)[72]  = reinterpret_cast<u16(*)[72]>(smem + 8704);
  u16 (*h3)[264] = reinterpret_cast<u16(*)[264]>(smem + 8704);

  const int t    = threadIdx.x;
  const int base = blockIdx.x * PTS;
  const int w    = t >> 6;
  const int lane = t & 63;

  // L0: 4 -> 64 fp32 straight from global (scalar-broadcast weights)
  {
    const int pt  = t & 31;
    const int grp = t >> 5;       // 0..7, 8 dims each
    const float4 pv = *reinterpret_cast<const float4*>(points + (size_t)(base + pt) * 4);
    #pragma unroll
    for (int j = 0; j < 8; ++j){
      const int m = grp * 8 + j;
      const float4 wv = *reinterpret_cast<const float4*>(w0 + m * 4);
      const float s = b0[m] + pv.x * wv.x + pv.y * wv.y + pv.z * wv.z + pv.w * wv.w;
      h1[pt][m] = f2bf(lrelu(s));
    }
  }
  __syncthreads();
  mfma_layer< 64, 128,  72, 136, true >(&h1[0][0], &h2[0][0], Whi + 0,     Wlo + 0,     b1, w, lane, nullptr);
  __syncthreads();
  mfma_layer<128, 256, 136, 264, true >(&h2[0][0], &h3[0][0], Whi + 8192,  Wlo + 8192,  b2, w, lane, nullptr);
  __syncthreads();
  f32x4 acc3[ATILES][4];
  mfma_layer<256, 256, 264,   1, false>(&h3[0][0], nullptr,   Whi + 40960, Wlo + 40960, b3, w, lane, acc3);

  // segment reduction (bias already baked per point)
  const int lrow = lane & 15;
  const int cF = find_cloud(idx, base);
  const int cL = find_cloud(idx, base + PTS - 1);
  if (cF == cL){
    #pragma unroll
    for (int mt = 0; mt < 4; ++mt){
      float s = 0.0f;
      #pragma unroll
      for (int a = 0; a < ATILES; ++a){
        const f32x4 v = acc3[a][mt];
        s += v[0] + v[1] + v[2] + v[3];
      }
      s += __shfl_xor(s, 16, 64);
      s += __shfl_xor(s, 32, 64);
      if (lane < 16)
        atomicAdd(sums + (size_t)cF * 256 + (w * 4 + mt) * 16 + lrow, s);
    }
  } else {
    const int g = lane >> 4;
    #pragma unroll
    for (int a = 0; a < ATILES; ++a)
      #pragma unroll
      for (int mt = 0; mt < 4; ++mt)
        #pragma unroll
        for (int r = 0; r < 4; ++r){
          const int pt = base + a * 16 + g * 4 + r;
          const int c  = find_cloud(idx, pt);
          atomicAdd(sums + (size_t)c * 256 + (w * 4 + mt) * 16 + lrow, acc3[a][mt][r]);
        }
  }
}

// ---- latent MLP: 4 clouds per block, 256 threads (thread = output dim) ----
__device__ __forceinline__ void lat_accum(const float (*__restrict__ in)[256],
    const float* __restrict__ W, const float* __restrict__ bias, int t, float acc[4])
{
  const float bv = bias[t];
  #pragma unroll
  for (int cl = 0; cl < 4; ++cl) acc[cl] = bv;
  const float4* __restrict__ wrow = reinterpret_cast<const float4*>(W + (size_t)t * 256);
  #pragma unroll 4
  for (int k4 = 0; k4 < 64; ++k4){
    const float4 w = wrow[k4];
    #pragma unroll
    for (int cl = 0; cl < 4; ++cl){
      const float4 a = *reinterpret_cast<const float4*>(&in[cl][k4 * 4]);
      acc[cl] += a.x * w.x + a.y * w.y + a.z * w.z + a.w * w.w;
    }
  }
}

__global__ __launch_bounds__(256)
void latent_kernel(const float* __restrict__ sums, const int* __restrict__ idx,
    const float* __restrict__ lw0, const float* __restrict__ lb0,
    const float* __restrict__ lw1, const float* __restrict__ lb1,
    const float* __restrict__ mw, const float* __restrict__ mb,
    const float* __restrict__ vw, const float* __restrict__ vb,
    float* __restrict__ out)
{
  __shared__ float s_in[4][256];
  __shared__ float s_a[4][256];
  const int t  = threadIdx.x;
  const int c0 = blockIdx.x * 4;

  #pragma unroll
  for (int cl = 0; cl < 4; ++cl){
    const int c = c0 + cl;
    const int cnt = idx[c] - (c ? idx[c - 1] : 0);
    s_in[cl][t] = sums[(size_t)c * 256 + t] / (float)cnt;
  }
  __syncthreads();

  float acc[4];
  lat_accum(s_in, lw0, lb0, t, acc);
  #pragma unroll
  for (int cl = 0; cl < 4; ++cl) s_a[cl][t] = lrelu(acc[cl]);
  __syncthreads();

  lat_accum(s_a, lw1, lb1, t, acc);
  __syncthreads();
  #pragma unroll
  for (int cl = 0; cl < 4; ++cl) s_in[cl][t] = lrelu(acc[cl]);
  __syncthreads();

  float accm[4], accv[4];
  lat_accum(s_in, mw, mb, t, accm);
  lat_accum(s_in, vw, vb, t, accv);
  #pragma unroll
  for (int cl = 0; cl < 4; ++cl){
    out[(size_t)(c0 + cl) * 256 + t]                    = accm[cl];  // mu
    out[(size_t)OUT_HALF + (size_t)(c0 + cl) * 256 + t] = accv[cl];  // log_var
  }
}

extern "C" void kernel_launch(void* const* d_in, const int* in_sizes, int n_in,
                              void* d_out, int out_size, void* d_ws, size_t ws_size,
                              hipStream_t stream) {
  const float* points = (const float*)d_in[0];
  const int*   idx    = (const int*)  d_in[1];
  const float* pw0 = (const float*)d_in[2],  *pb0 = (const float*)d_in[3];
  const float* pw1 = (const float*)d_in[4],  *pb1 = (const float*)d_in[5];
  const float* pw2 = (const float*)d_in[6],  *pb2 = (const float*)d_in[7];
  const float* pw3 = (const float*)d_in[8],  *pb3 = (const float*)d_in[9];
  const float* lw0 = (const float*)d_in[10], *lb0 = (const float*)d_in[11];
  const float* lw1 = (const float*)d_in[12], *lb1 = (const float*)d_in[13];
  const float* mw  = (const float*)d_in[14], *mb  = (const float*)d_in[15];
  const float* vw  = (const float*)d_in[16], *vb  = (const float*)d_in[17];
  float* out  = (float*)d_out;

  const size_t sums_bytes = (size_t)NB * 256 * sizeof(float);      // 4 MB
  const size_t wsplit_bytes = (size_t)WSPLIT_ELEMS * 2;            // 208 KB each
  float* sums; u16* Whi; u16* Wlo;
  if (ws_size >= sums_bytes + 2 * wsplit_bytes){
    sums = (float*)d_ws;
    Whi  = (u16*)((char*)d_ws + sums_bytes);
    Wlo  = Whi + WSPLIT_ELEMS;
  } else {
    // fallback: mu-half holds Wsplit (dead until latent writes mu at the end),
    // logvar-half holds sums (latent reads them just before writing log_var)
    Whi  = (u16*)d_out;
    Wlo  = Whi + WSPLIT_ELEMS;
    sums = out + OUT_HALF;
  }

  hipMemsetAsync(sums, 0, sums_bytes, stream);
  wsplit_kernel<<<WSPLIT_ELEMS / 256, 256, 0, stream>>>(pw1, pw2, pw3, Whi, Wlo);
  point_mfma_kernel<<<NTOT / PTS, 256, 0, stream>>>(points, idx,
      pw0, pb0, pb1, pb2, pb3, Whi, Wlo, sums);
  latent_kernel<<<NB / 4, 256, 0, stream>>>(sums, idx,
      lw0, lb0, lw1, lb1, mw, mb, vw, vb, out);
}

// Round 8
// 1097.788 us; speedup vs baseline: 2.1182x; 1.8595x over previous
//
#include <hip/hip_runtime.h>

// Encoder: point MLP (4->64->128->256->256) via split-bf16 MFMA + segment-mean
// pool + fp32 latent MLP.
// Round 8: m97-style async W-streaming.
//  - Static LDS <= 64 KB is a hard launch limit in this harness (r1/r3 aborts).
//  - LDS arena 49152 B: acts 32 KB (h3 overlays h2+h1; XOR-swizzled rows),
//    W double-buffer 2x8 KB. -> 3 blocks/CU.
//  - Weights pre-split hi/lo bf16, re-laid out CHUNK-major (52 x 8 KB chunks);
//    streamed global->LDS via __builtin_amdgcn_global_load_lds (width 16),
//    double-buffered, one barrier per chunk.
//  - Math identical to rounds 4-7 (absmax 0): A/B share the (lane,e)->k map;
//    C/D col=lane&15, row=(lane>>4)*4+reg (HW-verified m89).

#define NB    4096
#define NTOT  1048576
#define PTS   64
#define OUT_HALF (NB * 256)        // 1048576 floats
#define NCHUNK 52
#define CHUNK_U16 4096             // 8 KB per chunk
#define WSTG_ELEMS (NCHUNK * CHUNK_U16)   // 212992 u16 = 416 KB

typedef __attribute__((ext_vector_type(8))) short short8;
typedef __attribute__((ext_vector_type(4))) float f32x4;
typedef unsigned short u16;
typedef unsigned int   u32;
typedef __attribute__((address_space(1))) u32 gu32;
typedef __attribute__((address_space(3))) u32 lu32;

__device__ __forceinline__ float lrelu(float x){ return x > 0.0f ? x : 0.01f * x; }

__device__ __forceinline__ u16 f2bf(float x){            // round-to-nearest-even
  union{float f; u32 u;} v; v.f = x;
  u32 r = v.u + 0x7fffu + ((v.u >> 16) & 1u);
  return (u16)(r >> 16);
}
__device__ __forceinline__ float bf2f(u16 h){
  union{u32 u; float f;} v; v.u = ((u32)h) << 16; return v.f;
}

__device__ __forceinline__ int find_cloud(const int* __restrict__ idx, int j){
  int lo = 0, hi = NB;
  while (lo < hi){
    int mid = (lo + hi) >> 1;
    if (idx[mid] <= j) lo = mid + 1; else hi = mid;
  }
  return lo;
}

// ---- prologue: split W into hi/lo bf16, CHUNK-major -----------------------
// chunk g (8 KB = 4096 u16): [w(4)][hl(2)][frag 512], frag elem (lane,e).
// g-map: g<4: L1 (ks=g>>1, mt=g&1, MTW=2); g<20: L2 cc=g-4 (ks=cc>>2, mt=cc&3);
//        else L3 cc=g-20 (ks=cc>>2, mt=cc&3).
// elem: m=(w*MTW+mt)*16+(lane&15), k=ks*32+(lane>>4)*8+e; hl=0 hi, hl=1 lo.
__global__ void wsplit_kernel(const float* __restrict__ w1,
                              const float* __restrict__ w2,
                              const float* __restrict__ w3,
                              u16* __restrict__ Wstg){
  const int tid = blockIdx.x * 256 + threadIdx.x;   // 0..212991
  const int g = tid >> 12;
  const int r = tid & 4095;
  const float* W; int K, MTW, ks, mt;
  if (g < 4)      { W = w1; K = 64;  MTW = 2; ks = g >> 1;  mt = g & 1; }
  else if (g < 20){ int cc = g - 4;  W = w2; K = 128; MTW = 4; ks = cc >> 2; mt = cc & 3; }
  else            { int cc = g - 20; W = w3; K = 256; MTW = 4; ks = cc >> 2; mt = cc & 3; }
  const int w    = r >> 10;
  const int rem  = r & 1023;
  const int hl   = rem >> 9;
  const int fe   = rem & 511;
  const int lane = fe >> 3, e = fe & 7;
  const int m = (w * MTW + mt) * 16 + (lane & 15);
  const int k = ks * 32 + (lane >> 4) * 8 + e;
  const float v = W[(size_t)m * K + k];
  const u16 hi = f2bf(v);
  Wstg[tid] = hl ? f2bf(v - bf2f(hi)) : hi;
}

// ---- async stage of one 8 KB chunk into wbuf[parity] ----------------------
__device__ __forceinline__ void stage_chunk(const u16* __restrict__ Wstg,
                                            char* wbuf, int gc, int t){
  const u16* src = Wstg + ((size_t)gc << 12) + t * 8;
  char* dst = wbuf + ((gc & 1) << 13) + t * 16;
  __builtin_amdgcn_global_load_lds((const gu32*)(src),        (lu32*)(dst),        16, 0, 0);
  __builtin_amdgcn_global_load_lds((const gu32*)(src + 2048), (lu32*)(dst + 4096), 16, 0, 0);
}

// ---- one layer: K -> M over 64 points; wave w owns m-quarter ---------------
// Chunk loop fully unrolled (compile-time mt). One __syncthreads per chunk.
template<int K, int M, int RBI, int RBO, int GBASE, bool WRITE, bool PRE_BAR>
__device__ __forceinline__ void layer_run(
    const char* hin, char* hout, const u16* __restrict__ Wstg, char* wbuf,
    const float* __restrict__ bias, int w, int lane, int t, f32x4 (*accRet)[4])
{
  constexpr int KS = K / 32, MTW = M / 64, NCH = KS * MTW;
  const int lrow = lane & 15, g = lane >> 4;
  f32x4 acc[4][MTW];
  #pragma unroll
  for (int mt = 0; mt < MTW; ++mt){
    const float bv = bias[(w * MTW + mt) * 16 + lrow];
    #pragma unroll
    for (int a = 0; a < 4; ++a){
      acc[a][mt][0] = bv; acc[a][mt][1] = bv; acc[a][mt][2] = bv; acc[a][mt][3] = bv;
    }
  }
  short8 af[4];
  #pragma unroll
  for (int c = 0; c < NCH; ++c){
    const int gc = GBASE + c;
    if (gc + 1 < NCHUNK) stage_chunk(Wstg, wbuf, gc + 1, t);
    const int ks = c / MTW, mt = c % MTW;       // compile-time after unroll
    if (mt == 0){
      const int ko = ks * 64 + g * 16;
      #pragma unroll
      for (int a = 0; a < 4; ++a){
        const int pt = a * 16 + lrow;
        af[a] = *reinterpret_cast<const short8*>(hin + pt * RBI + (ko ^ ((pt & 7) << 4)));
      }
    }
    const char* wb = wbuf + ((gc & 1) << 13) + (w << 11) + (lane << 4);
    const short8 bh = *reinterpret_cast<const short8*>(wb);
    const short8 bl = *reinterpret_cast<const short8*>(wb + 1024);
    #pragma unroll
    for (int a = 0; a < 4; ++a)
      acc[a][mt] = __builtin_amdgcn_mfma_f32_16x16x32_bf16(af[a], bh, acc[a][mt], 0, 0, 0);
    #pragma unroll
    for (int a = 0; a < 4; ++a)
      acc[a][mt] = __builtin_amdgcn_mfma_f32_16x16x32_bf16(af[a], bl, acc[a][mt], 0, 0, 0);
    if (c == NCH - 1){
      if constexpr (PRE_BAR) __syncthreads();   // last hin reads done before hout overlays
      if constexpr (WRITE){
        #pragma unroll
        for (int a = 0; a < 4; ++a)
          #pragma unroll
          for (int mt2 = 0; mt2 < MTW; ++mt2){
            const int m = (w * MTW + mt2) * 16 + lrow;
            #pragma unroll
            for (int r2 = 0; r2 < 4; ++r2){
              const int pt = a * 16 + g * 4 + r2;
              *reinterpret_cast<u16*>(hout + pt * RBO + ((m * 2) ^ ((pt & 7) << 4)))
                  = f2bf(lrelu(acc[a][mt2][r2]));
            }
          }
      }
    }
    __syncthreads();
  }
  if constexpr (!WRITE){
    #pragma unroll
    for (int a = 0; a < 4; ++a)
      #pragma unroll
      for (int mt2 = 0; mt2 < MTW; ++mt2)
        accRet[a][mt2] = acc[a][mt2];
  }
}

__global__ __launch_bounds__(256, 3)
void point_mfma_kernel(const float* __restrict__ points, const int* __restrict__ idx,
    const float* __restrict__ w0, const float* __restrict__ b0,
    const float* __restrict__ b1, const float* __restrict__ b2,
    const float* __restrict__ b3,
    const u16* __restrict__ Wstg,
    float* __restrict__ sums)
{
  // LDS arena (49152 B, 3 blocks/CU):
  //   h2 @ [0,16384)      rows 256 B   live: L1-epilogue .. L2 A-reads
  //   h1 @ [16384,24576)  rows 128 B   live: L0 .. L1 A-reads
  //   h3 @ [0,32768)      rows 512 B   live: L2-epilogue .. L3 A-reads
  //        (overlays h2+h1, both dead by then; PRE_BAR guards the handoff)
  //   wbuf @ [32768,49152) 2 x 8 KB W chunk double-buffer
  __shared__ __align__(16) char smem[49152];
  char* h3   = smem;
  char* h2   = smem;
  char* h1   = smem + 16384;
  char* wbuf = smem + 32768;

  const int t    = threadIdx.x;
  const int base = blockIdx.x * PTS;
  const int w    = t >> 6;
  const int lane = t & 63;

  stage_chunk(Wstg, wbuf, 0, t);       // async; drained by the L0 barrier

  // L0: 4 -> 64 fp32 straight from global (broadcast weights)
  {
    const int pt  = t & 63;
    const int grp = t >> 6;            // 0..3, 16 dims each
    const float4 pv = *reinterpret_cast<const float4*>(points + (size_t)(base + pt) * 4);
    #pragma unroll
    for (int j = 0; j < 16; ++j){
      const int m = grp * 16 + j;
      const float4 wv = *reinterpret_cast<const float4*>(w0 + m * 4);
      const float s = b0[m] + pv.x * wv.x + pv.y * wv.y + pv.z * wv.z + pv.w * wv.w;
      *reinterpret_cast<u16*>(h1 + pt * 128 + ((m * 2) ^ ((pt & 7) << 4))) = f2bf(lrelu(s));
    }
  }
  __syncthreads();

  layer_run< 64, 128, 128, 256,  0, true,  false>(h1, h2, Wstg, wbuf, b1, w, lane, t, nullptr);
  layer_run<128, 256, 256, 512,  4, true,  true >(h2, h3, Wstg, wbuf, b2, w, lane, t, nullptr);
  f32x4 acc3[4][4];
  layer_run<256, 256, 512,   1, 20, false, false>(h3, nullptr, Wstg, wbuf, b3, w, lane, t, acc3);

  // segment reduction (bias baked per point)
  const int lrow = lane & 15;
  const int cF = find_cloud(idx, base);
  const int cL = find_cloud(idx, base + PTS - 1);
  if (cF == cL){
    #pragma unroll
    for (int mt = 0; mt < 4; ++mt){
      float s = 0.0f;
      #pragma unroll
      for (int a = 0; a < 4; ++a){
        const f32x4 v = acc3[a][mt];
        s += v[0] + v[1] + v[2] + v[3];
      }
      s += __shfl_xor(s, 16, 64);
      s += __shfl_xor(s, 32, 64);
      if (lane < 16)
        atomicAdd(sums + (size_t)cF * 256 + (w * 4 + mt) * 16 + lrow, s);
    }
  } else {
    const int g = lane >> 4;
    #pragma unroll
    for (int a = 0; a < 4; ++a)
      #pragma unroll
      for (int mt = 0; mt < 4; ++mt)
        #pragma unroll
        for (int r = 0; r < 4; ++r){
          const int pt = base + a * 16 + g * 4 + r;
          const int c  = find_cloud(idx, pt);
          atomicAdd(sums + (size_t)c * 256 + (w * 4 + mt) * 16 + lrow, acc3[a][mt][r]);
        }
  }
}

// ---- latent MLP: 16 clouds per block, 256 threads (thread = output dim) ----
#define CPB 16
__device__ __forceinline__ void lat_accum(const float (*__restrict__ in)[256],
    const float* __restrict__ W, const float* __restrict__ bias, int t, float* acc)
{
  const float bv = bias[t];
  #pragma unroll
  for (int cl = 0; cl < CPB; ++cl) acc[cl] = bv;
  const float4* __restrict__ wrow = reinterpret_cast<const float4*>(W + (size_t)t * 256);
  #pragma unroll 4
  for (int k4 = 0; k4 < 64; ++k4){
    const float4 w = wrow[k4];
    #pragma unroll
    for (int cl = 0; cl < CPB; ++cl){
      const float4 a = *reinterpret_cast<const float4*>(&in[cl][k4 * 4]);
      acc[cl] += a.x * w.x + a.y * w.y + a.z * w.z + a.w * w.w;
    }
  }
}

__global__ __launch_bounds__(256)
void latent_kernel(const float* __restrict__ sums, const int* __restrict__ idx,
    const float* __restrict__ lw0, const float* __restrict__ lb0,
    const float* __restrict__ lw1, const float* __restrict__ lb1,
    const float* __restrict__ mw, const float* __restrict__ mb,
    const float* __restrict__ vw, const float* __restrict__ vb,
    float* __restrict__ out)
{
  __shared__ float s_in[CPB][256];
  __shared__ float s_a[CPB][256];
  const int t  = threadIdx.x;
  const int c0 = blockIdx.x * CPB;

  #pragma unroll
  for (int cl = 0; cl < CPB; ++cl){
    const int c = c0 + cl;
    const int cnt = idx[c] - (c ? idx[c - 1] : 0);
    s_in[cl][t] = sums[(size_t)c * 256 + t] / (float)cnt;
  }
  __syncthreads();

  float acc[CPB];
  lat_accum(s_in, lw0, lb0, t, acc);
  #pragma unroll
  for (int cl = 0; cl < CPB; ++cl) s_a[cl][t] = lrelu(acc[cl]);
  __syncthreads();

  lat_accum(s_a, lw1, lb1, t, acc);
  __syncthreads();
  #pragma unroll
  for (int cl = 0; cl < CPB; ++cl) s_in[cl][t] = lrelu(acc[cl]);
  __syncthreads();

  float accm[CPB], accv[CPB];
  lat_accum(s_in, mw, mb, t, accm);
  lat_accum(s_in, vw, vb, t, accv);
  #pragma unroll
  for (int cl = 0; cl < CPB; ++cl){
    out[(size_t)(c0 + cl) * 256 + t]                    = accm[cl];  // mu
    out[(size_t)OUT_HALF + (size_t)(c0 + cl) * 256 + t] = accv[cl];  // log_var
  }
}

extern "C" void kernel_launch(void* const* d_in, const int* in_sizes, int n_in,
                              void* d_out, int out_size, void* d_ws, size_t ws_size,
                              hipStream_t stream) {
  const float* points = (const float*)d_in[0];
  const int*   idx    = (const int*)  d_in[1];
  const float* pw0 = (const float*)d_in[2],  *pb0 = (const float*)d_in[3];
  const float* pw1 = (const float*)d_in[4],  *pb1 = (const float*)d_in[5];
  const float* pw2 = (const float*)d_in[6],  *pb2 = (const float*)d_in[7];
  const float* pw3 = (const float*)d_in[8],  *pb3 = (const float*)d_in[9];
  const float* lw0 = (const float*)d_in[10], *lb0 = (const float*)d_in[11];
  const float* lw1 = (const float*)d_in[12], *lb1 = (const float*)d_in[13];
  const float* mw  = (const float*)d_in[14], *mb  = (const float*)d_in[15];
  const float* vw  = (const float*)d_in[16], *vb  = (const float*)d_in[17];
  float* out  = (float*)d_out;

  const size_t sums_bytes = (size_t)NB * 256 * sizeof(float);      // 4 MB
  const size_t wstg_bytes = (size_t)WSTG_ELEMS * 2;                // 416 KB
  float* sums; u16* Wstg;
  if (ws_size >= sums_bytes + wstg_bytes){
    sums = (float*)d_ws;
    Wstg = (u16*)((char*)d_ws + sums_bytes);
  } else {
    // fallback: mu-half holds Wstg (dead until latent writes mu at the end),
    // logvar-half holds sums (latent reads them just before writing log_var)
    Wstg = (u16*)d_out;
    sums = out + OUT_HALF;
  }

  hipMemsetAsync(sums, 0, sums_bytes, stream);
  wsplit_kernel<<<WSTG_ELEMS / 256, 256, 0, stream>>>(pw1, pw2, pw3, Wstg);
  point_mfma_kernel<<<NTOT / PTS, 256, 0, stream>>>(points, idx,
      pw0, pb0, pb1, pb2, pb3, Wstg, sums);
  latent_kernel<<<NB / CPB, 256, 0, stream>>>(sums, idx,
      lw0, lb0, lw1, lb1, mw, mb, vw, vb, out);
}

// Round 12
// 1083.603 us; speedup vs baseline: 2.1459x; 1.0131x over previous
//
#include <hip/hip_runtime.h>

// Encoder round 12: REVERT the (empirically poisoned) L3-hoist; back to the
// round-5 validated math (passed, absmax 0.0): full point MLP incl. L3 via
// split-bf16 MFMA, pool acc3, fp32 latent. Schedule-only change vs round 5:
// mfma_layer loops reordered mt-outer with per-mt B-fragment clusters of
// 4 ks (8 independent 16B loads) for deeper memory-level parallelism.
// Per-accumulator arithmetic order (ks ascending, hi before lo) unchanged
// -> bit-identical math to round 5. Latent = round-8's validated CPB=16.

#define NB    4096
#define NTOT  1048576
#define PTS   64
#define OUT_HALF (NB * 256)       // 1048576 floats
#define WSPLIT_ELEMS 106496       // 8192 + 32768 + 65536 frag-elems per array

typedef __attribute__((ext_vector_type(8))) short short8;
typedef __attribute__((ext_vector_type(4))) float f32x4;
typedef unsigned short u16;
typedef unsigned int   u32;

__device__ __forceinline__ float lrelu(float x){ return x > 0.0f ? x : 0.01f * x; }

__device__ __forceinline__ u16 f2bf(float x){            // round-to-nearest-even
  union{float f; u32 u;} v; v.f = x;
  u32 r = v.u + 0x7fffu + ((v.u >> 16) & 1u);
  return (u16)(r >> 16);
}
__device__ __forceinline__ float bf2f(u16 h){
  union{u32 u; float f;} v; v.u = ((u32)h) << 16; return v.f;
}

__device__ __forceinline__ int find_cloud(const int* __restrict__ idx, int j){
  int lo = 0, hi = NB;
  while (lo < hi){
    int mid = (lo + hi) >> 1;
    if (idx[mid] <= j) lo = mid + 1; else hi = mid;
  }
  return lo;
}

// ---- prologue: split W1/W2/W3 into hi/lo bf16, fragment-major (r5 map) ----
// frag = 512 elems [lane][e]; elem (lane,e) = W[mtg*16+(lane&15)]
// [ks*32+(lane>>4)*8+e]; fragId = mtg*KS+ks. Offsets: L1=0, L2=8192, L3=40960.
__global__ void wsplit_kernel(const float* __restrict__ w1,
                              const float* __restrict__ w2,
                              const float* __restrict__ w3,
                              u16* __restrict__ Whi, u16* __restrict__ Wlo){
  const int tid = blockIdx.x * 256 + threadIdx.x;   // 0..106495
  const float* W; int K, off;
  if (tid < 8192)       { W = w1; K = 64;  off = 0; }
  else if (tid < 40960) { W = w2; K = 128; off = 8192; }
  else                  { W = w3; K = 256; off = 40960; }
  const int t      = tid - off;
  const int fragId = t >> 9;
  const int r      = t & 511;
  const int lane   = r >> 3, e = r & 7;
  const int KS     = K / 32;
  const int ks     = fragId % KS, mtg = fragId / KS;
  const int m      = mtg * 16 + (lane & 15);
  const int k      = ks * 32 + (lane >> 4) * 8 + e;
  const float v = W[(size_t)m * K + k];
  const u16 hi = f2bf(v);
  Whi[tid] = hi;
  Wlo[tid] = f2bf(v - bf2f(hi));
}

// ---- one MFMA layer: K -> M over 64 points; wave w owns m-quarter ---------
// mt-outer; per mt, B-fragments loaded in clusters of up to 4 ks (8
// independent dwordx4 loads) before the MFMA chain. Arithmetic order per
// accumulator identical to round 5 (ks ascending, hi before lo).
template<int K, int M, int LDSKI, int LDSKO, bool WRITE>
__device__ __forceinline__ void mfma_layer(
    const u16* __restrict__ hin, u16* __restrict__ hout,
    const u16* __restrict__ Whi, const u16* __restrict__ Wlo,
    const float* __restrict__ bias, int w, int lane, f32x4 (*__restrict__ accRet)[4])
{
  constexpr int KS  = K / 32;
  constexpr int MTW = M / 64;
  constexpr int KC  = (KS < 4) ? KS : 4;      // B-cluster depth
  const int lrow = lane & 15;   // A-row (pt in tile) == B/D col (m in tile)
  const int g    = lane >> 4;   // k-slice group / D row group

  f32x4 acc[4][MTW];
  #pragma unroll
  for (int mt = 0; mt < MTW; ++mt){
    const float bv = bias[(w * MTW + mt) * 16 + lrow];
    #pragma unroll
    for (int a = 0; a < 4; ++a){
      acc[a][mt][0] = bv; acc[a][mt][1] = bv; acc[a][mt][2] = bv; acc[a][mt][3] = bv;
    }
  }

  // fragment (mt, ks) lives at (mt*KS + ks)*512 + lane*8 past these bases
  const u16* __restrict__ bptr = Whi + (size_t)(w * MTW) * KS * 512 + lane * 8;
  const u16* __restrict__ lptr = Wlo + (size_t)(w * MTW) * KS * 512 + lane * 8;

  #pragma unroll
  for (int mt = 0; mt < MTW; ++mt){
    #pragma unroll
    for (int kc = 0; kc < KS; kc += KC){
      short8 bh[KC], bl[KC];
      #pragma unroll
      for (int i = 0; i < KC; ++i){
        bh[i] = *reinterpret_cast<const short8*>(bptr + (size_t)(mt * KS + kc + i) * 512);
        bl[i] = *reinterpret_cast<const short8*>(lptr + (size_t)(mt * KS + kc + i) * 512);
      }
      #pragma unroll
      for (int i = 0; i < KC; ++i){
        const int ks = kc + i;
        short8 af[4];
        const int eoff = ks * 32 + g * 8;
        #pragma unroll
        for (int a = 0; a < 4; ++a)
          af[a] = *reinterpret_cast<const short8*>(hin + (a * 16 + lrow) * LDSKI + eoff);
        #pragma unroll
        for (int a = 0; a < 4; ++a)
          acc[a][mt] = __builtin_amdgcn_mfma_f32_16x16x32_bf16(af[a], bh[i], acc[a][mt], 0, 0, 0);
        #pragma unroll
        for (int a = 0; a < 4; ++a)
          acc[a][mt] = __builtin_amdgcn_mfma_f32_16x16x32_bf16(af[a], bl[i], acc[a][mt], 0, 0, 0);
      }
    }
  }

  if constexpr (WRITE){
    #pragma unroll
    for (int a = 0; a < 4; ++a)
      #pragma unroll
      for (int mt = 0; mt < MTW; ++mt){
        const int m = (w * MTW + mt) * 16 + lrow;
        #pragma unroll
        for (int r = 0; r < 4; ++r){
          const int pt = a * 16 + g * 4 + r;      // D row = point
          hout[pt * LDSKO + m] = f2bf(lrelu(acc[a][mt][r]));
        }
      }
  } else {
    #pragma unroll
    for (int a = 0; a < 4; ++a)
      #pragma unroll
      for (int mt = 0; mt < MTW; ++mt)
        accRet[a][mt] = acc[a][mt];
  }
}

__global__ __launch_bounds__(256, 3)
void point_mfma_kernel(const float* __restrict__ points, const int* __restrict__ idx,
    const float* __restrict__ w0, const float* __restrict__ b0,
    const float* __restrict__ b1, const float* __restrict__ b2,
    const float* __restrict__ b3,
    const u16* __restrict__ Whi, const u16* __restrict__ Wlo,
    float* __restrict__ sums)
{
  // Overlapped LDS arena (51200 B -> 3 blocks/CU), exactly round 5:
  //   h2 @ 0      (17408 B)   live: L1-write .. L2-read
  //   h1 @ 17408  ( 9216 B)   live: L0-write .. L1-read
  //   h3 @ 17408  (33792 B)   live: L2-write .. L3-read (h1 dead by then)
  __shared__ __align__(16) char smem[51200];
  u16 (*h2)[136] = reinterpret_cast<u16(*)[136]>(smem);
  u16 (*h1)[72]  = reinterpret_cast<u16(*)[72]>(smem + 17408);
  u16 (*h3)[264] = reinterpret_cast<u16(*)[264]>(smem + 17408);

  const int t    = threadIdx.x;
  const int base = blockIdx.x * PTS;
  const int w    = t >> 6;
  const int lane = t & 63;

  // L0: 4 -> 64 fp32 straight from global (round-5 code)
  {
    const int pt  = t & 63;
    const int grp = t >> 6;
    const float4 pv = *reinterpret_cast<const float4*>(points + (size_t)(base + pt) * 4);
    #pragma unroll
    for (int j = 0; j < 16; ++j){
      const int m = grp * 16 + j;
      const float4 wv = *reinterpret_cast<const float4*>(w0 + m * 4);
      const float s = b0[m] + pv.x * wv.x + pv.y * wv.y + pv.z * wv.z + pv.w * wv.w;
      h1[pt][m] = f2bf(lrelu(s));
    }
  }
  __syncthreads();
  mfma_layer< 64, 128,  72, 136, true >(&h1[0][0], &h2[0][0], Whi + 0,     Wlo + 0,     b1, w, lane, nullptr);
  __syncthreads();
  mfma_layer<128, 256, 136, 264, true >(&h2[0][0], &h3[0][0], Whi + 8192,  Wlo + 8192,  b2, w, lane, nullptr);
  __syncthreads();
  f32x4 acc3[4][4];
  mfma_layer<256, 256, 264,   1, false>(&h3[0][0], nullptr,   Whi + 40960, Wlo + 40960, b3, w, lane, acc3);

  // segment reduction (bias already baked per point) — round-5 code
  const int lrow = lane & 15;
  const int cF = find_cloud(idx, base);
  const int cL = find_cloud(idx, base + PTS - 1);
  if (cF == cL){
    #pragma unroll
    for (int mt = 0; mt < 4; ++mt){
      float s = 0.0f;
      #pragma unroll
      for (int a = 0; a < 4; ++a){
        const f32x4 v = acc3[a][mt];
        s += v[0] + v[1] + v[2] + v[3];
      }
      s += __shfl_xor(s, 16, 64);
      s += __shfl_xor(s, 32, 64);
      if (lane < 16)
        atomicAdd(sums + (size_t)cF * 256 + (w * 4 + mt) * 16 + lrow, s);
    }
  } else {
    const int g = lane >> 4;
    #pragma unroll
    for (int a = 0; a < 4; ++a)
      #pragma unroll
      for (int mt = 0; mt < 4; ++mt)
        #pragma unroll
        for (int r = 0; r < 4; ++r){
          const int pt = base + a * 16 + g * 4 + r;
          const int c  = find_cloud(idx, pt);
          atomicAdd(sums + (size_t)c * 256 + (w * 4 + mt) * 16 + lrow, acc3[a][mt][r]);
        }
  }
}

// ---- latent MLP: round-8 PASSED kernel, verbatim (CPB=16) -----------------
#define CPB 16
__device__ __forceinline__ void lat_accum(const float (*__restrict__ in)[256],
    const float* __restrict__ W, const float* __restrict__ bias, int t, float* acc)
{
  const float bv = bias[t];
  #pragma unroll
  for (int cl = 0; cl < CPB; ++cl) acc[cl] = bv;
  const float4* __restrict__ wrow = reinterpret_cast<const float4*>(W + (size_t)t * 256);
  #pragma unroll 4
  for (int k4 = 0; k4 < 64; ++k4){
    const float4 w = wrow[k4];
    #pragma unroll
    for (int cl = 0; cl < CPB; ++cl){
      const float4 a = *reinterpret_cast<const float4*>(&in[cl][k4 * 4]);
      acc[cl] += a.x * w.x + a.y * w.y + a.z * w.z + a.w * w.w;
    }
  }
}

__global__ __launch_bounds__(256)
void latent_kernel(const float* __restrict__ sums, const int* __restrict__ idx,
    const float* __restrict__ lw0, const float* __restrict__ lb0,
    const float* __restrict__ lw1, const float* __restrict__ lb1,
    const float* __restrict__ mw, const float* __restrict__ mb,
    const float* __restrict__ vw, const float* __restrict__ vb,
    float* __restrict__ out)
{
  __shared__ float s_in[CPB][256];
  __shared__ float s_a[CPB][256];
  const int t  = threadIdx.x;
  const int c0 = blockIdx.x * CPB;

  #pragma unroll
  for (int cl = 0; cl < CPB; ++cl){
    const int c = c0 + cl;
    const int cnt = idx[c] - (c ? idx[c - 1] : 0);
    s_in[cl][t] = sums[(size_t)c * 256 + t] / (float)cnt;
  }
  __syncthreads();

  float acc[CPB];
  lat_accum(s_in, lw0, lb0, t, acc);
  #pragma unroll
  for (int cl = 0; cl < CPB; ++cl) s_a[cl][t] = lrelu(acc[cl]);
  __syncthreads();

  lat_accum(s_a, lw1, lb1, t, acc);
  __syncthreads();
  #pragma unroll
  for (int cl = 0; cl < CPB; ++cl) s_in[cl][t] = lrelu(acc[cl]);
  __syncthreads();

  float accm[CPB], accv[CPB];
  lat_accum(s_in, mw, mb, t, accm);
  lat_accum(s_in, vw, vb, t, accv);
  #pragma unroll
  for (int cl = 0; cl < CPB; ++cl){
    out[(size_t)(c0 + cl) * 256 + t]                    = accm[cl];  // mu
    out[(size_t)OUT_HALF + (size_t)(c0 + cl) * 256 + t] = accv[cl];  // log_var
  }
}

extern "C" void kernel_launch(void* const* d_in, const int* in_sizes, int n_in,
                              void* d_out, int out_size, void* d_ws, size_t ws_size,
                              hipStream_t stream) {
  const float* points = (const float*)d_in[0];
  const int*   idx    = (const int*)  d_in[1];
  const float* pw0 = (const float*)d_in[2],  *pb0 = (const float*)d_in[3];
  const float* pw1 = (const float*)d_in[4],  *pb1 = (const float*)d_in[5];
  const float* pw2 = (const float*)d_in[6],  *pb2 = (const float*)d_in[7];
  const float* pw3 = (const float*)d_in[8],  *pb3 = (const float*)d_in[9];
  const float* lw0 = (const float*)d_in[10], *lb0 = (const float*)d_in[11];
  const float* lw1 = (const float*)d_in[12], *lb1 = (const float*)d_in[13];
  const float* mw  = (const float*)d_in[14], *mb  = (const float*)d_in[15];
  const float* vw  = (const float*)d_in[16], *vb  = (const float*)d_in[17];
  float* out  = (float*)d_out;

  const size_t sums_bytes = (size_t)NB * 256 * sizeof(float);      // 4 MB
  const size_t wsplit_bytes = (size_t)WSPLIT_ELEMS * 2;            // 208 KB each
  float* sums; u16* Whi; u16* Wlo;
  if (ws_size >= sums_bytes + 2 * wsplit_bytes){
    sums = (float*)d_ws;
    Whi  = (u16*)((char*)d_ws + sums_bytes);
    Wlo  = Whi + WSPLIT_ELEMS;
  } else {
    // fallback: mu-half holds Wsplit (dead until latent writes mu at the end),
    // logvar-half holds sums (latent reads them just before writing log_var)
    Whi  = (u16*)d_out;
    Wlo  = Whi + WSPLIT_ELEMS;
    sums = out + OUT_HALF;
  }

  hipMemsetAsync(sums, 0, sums_bytes, stream);
  wsplit_kernel<<<WSPLIT_ELEMS / 256, 256, 0, stream>>>(pw1, pw2, pw3, Whi, Wlo);
  point_mfma_kernel<<<NTOT / PTS, 256, 0, stream>>>(points, idx,
      pw0, pb0, pb1, pb2, pb3, Whi, Wlo, sums);
  latent_kernel<<<NB / CPB, 256, 0, stream>>>(sums, idx,
      lw0, lb0, lw1, lb1, mw, mb, vw, vb, out);
}